// Round 16
// baseline (220.981 us; speedup 1.0000x reference)
//
#include <hip/hip_runtime.h>
#include <hip/hip_bf16.h>
#include <math.h>

// ---------------- problem constants ----------------
#define Dmod   1024
#define NHmod  16
#define DHmod  64
#define Bmod   2
#define Nmod   2048
#define Mrows  (Bmod * Nmod)        // 4096
#define FF     (4 * Dmod)           // 4096
#define EPSLN  1e-5f

typedef __attribute__((ext_vector_type(8))) short bf16x8;
typedef __attribute__((ext_vector_type(4))) float f32x4;
typedef unsigned short ushort_t;
typedef unsigned int uint_t;

#define MFMA16x16x32(a, b, c) __builtin_amdgcn_mfma_f32_16x16x32_bf16((a), (b), (c), 0, 0, 0)

#define AS1 __attribute__((address_space(1)))
#define AS3 __attribute__((address_space(3)))

__device__ __forceinline__ void gload_lds16(const ushort_t* g, ushort_t* l) {
    __builtin_amdgcn_global_load_lds((const AS1 uint_t*)(const void*)g,
                                     (AS3 uint_t*)(void*)l, 16, 0, 0);
}

__device__ __forceinline__ ushort_t f2bf(float f) {
    union { float f; uint_t u; } v; v.f = f;
    uint_t r = v.u + 0x7FFFu + ((v.u >> 16) & 1u);   // RNE
    return (ushort_t)(r >> 16);
}

__device__ __forceinline__ float bf2f(uint_t u) {
    union { float f; uint_t u; } v; v.u = u << 16;
    return v.f;
}

// ---------------- fused fp32->bf16 weight conversion ----------------
__global__ __launch_bounds__(256) void cvt_kernel(const float* __restrict__ Wq, const float* __restrict__ Wk,
                                                  const float* __restrict__ Wv, const float* __restrict__ Wo,
                                                  const float* __restrict__ W1, const float* __restrict__ W2,
                                                  ushort_t* __restrict__ qkv, ushort_t* __restrict__ wo,
                                                  ushort_t* __restrict__ w1, ushort_t* __restrict__ w2) {
    int u = blockIdx.x * 256 + threadIdx.x;
    const float* src; ushort_t* dst; int i;
    float scale = 1.0f;
    if (u < 393216) {
        if (u < 131072)      { src = Wq; dst = qkv;           i = u; scale = 0.125f; }
        else if (u < 262144) { src = Wk; dst = qkv + 1048576; i = u - 131072; }
        else                 { src = Wv; dst = qkv + 2097152; i = u - 262144; }
    } else if (u < 524288)   { src = Wo; dst = wo; i = u - 393216; }
    else if (u < 1048576)    { src = W1; dst = w1; i = u - 524288; }
    else                     { src = W2; dst = w2; i = u - 1048576; }
    float4 a = ((const float4*)src)[2 * i];
    float4 b = ((const float4*)src)[2 * i + 1];
    uint4 o;
    o.x = (uint_t)f2bf(a.x * scale) | ((uint_t)f2bf(a.y * scale) << 16);
    o.y = (uint_t)f2bf(a.z * scale) | ((uint_t)f2bf(a.w * scale) << 16);
    o.z = (uint_t)f2bf(b.x * scale) | ((uint_t)f2bf(b.y * scale) << 16);
    o.w = (uint_t)f2bf(b.z * scale) | ((uint_t)f2bf(b.w * scale) << 16);
    ((uint4*)dst)[i] = o;
}

// ---------------- LayerNorm -> bf16 out ----------------
__global__ __launch_bounds__(256) void ln_bf_kernel(const float* __restrict__ x,
                                                    const float* __restrict__ scale,
                                                    const float* __restrict__ shift,
                                                    ushort_t* __restrict__ out) {
    int row = blockIdx.x;
    const float4* xr = (const float4*)(x + (size_t)row * Dmod);
    float4 v = xr[threadIdx.x];
    float s  = v.x + v.y + v.z + v.w;
    float s2 = v.x*v.x + v.y*v.y + v.z*v.z + v.w*v.w;

    __shared__ float rs[8], rs2[8];
    #pragma unroll
    for (int o = 32; o; o >>= 1) { s += __shfl_down(s, o); s2 += __shfl_down(s2, o); }
    int wave = threadIdx.x >> 6, lane = threadIdx.x & 63;
    if (lane == 0) { rs[wave] = s; rs2[wave] = s2; }
    __syncthreads();
    if (threadIdx.x == 0) {
        rs[0]  = rs[0] + rs[1] + rs[2] + rs[3];
        rs2[0] = rs2[0] + rs2[1] + rs2[2] + rs2[3];
    }
    __syncthreads();
    float mean = rs[0] * (1.0f / Dmod);
    float var  = rs2[0] * (1.0f / Dmod) - mean * mean;
    float rstd = rsqrtf(var + EPSLN);

    float4 sc = ((const float4*)scale)[threadIdx.x];
    float4 sh = ((const float4*)shift)[threadIdx.x];
    uint2 o;
    o.x = (uint_t)f2bf(sc.x * (v.x - mean) * rstd + sh.x) |
          ((uint_t)f2bf(sc.y * (v.y - mean) * rstd + sh.y) << 16);
    o.y = (uint_t)f2bf(sc.z * (v.z - mean) * rstd + sh.z) |
          ((uint_t)f2bf(sc.w * (v.w - mean) * rstd + sh.w) << 16);
    ((uint2*)(out + (size_t)row * Dmod))[threadIdx.x] = o;
}

// ---------------- GELU via sigmoid identity ----------------
__device__ __forceinline__ float gelu_f(float x) {
    const float c = 0.7978845608028654f;     // sqrt(2/pi)
    float u = c * (x + 0.044715f * x * x * x);
    return x / (1.0f + __expf(-2.0f * u));
}

// ================ 256x256 BK64 8-wave GEMM, 8-PHASE + counted lgkm ================
// As round 15 (m201 port) plus counted lgkmcnt INSIDE each phase: reads issue
// in order, then lgkm(3)/(2)/(1)/(0) gates 4-MFMA groups (b-major in qm phases,
// a-major in the reuse phases), each pinned with sched_barrier(0) (T18).
// vmcnt ledger unchanged: vmcnt(4) at ends of p1/p3 (p1 of last tile: vmcnt(0)).
// MODE 0: QKV scatter; 2: +bias GELU bf16; 4: bf16 split-K partial.
#define DSR(D, A, OFF) asm volatile("ds_read_b128 %0, %1 offset:" OFF : "=v"(D) : "v"(A))
#define SB0 __builtin_amdgcn_sched_barrier(0)
#define BARR __builtin_amdgcn_s_barrier()
#define LGKM(N) asm volatile("s_waitcnt lgkmcnt(" #N ")" ::)

#define GRP_QM0(J, B) \
  acc[0][J]=MFMA16x16x32(a0,B,acc[0][J]); acc[1][J]=MFMA16x16x32(a1,B,acc[1][J]); \
  acc[2][J]=MFMA16x16x32(a2,B,acc[2][J]); acc[3][J]=MFMA16x16x32(a3,B,acc[3][J]);
#define GRP_QM1(I, A) \
  acc[I][0]=MFMA16x16x32(A,b0,acc[I][0]); acc[I][1]=MFMA16x16x32(A,b1,acc[I][1]); \
  acc[I][2]=MFMA16x16x32(A,b2,acc[I][2]); acc[I][3]=MFMA16x16x32(A,b3,acc[I][3]);

template <int MODE>
__global__ __launch_bounds__(512, 2) void gemm256(const ushort_t* __restrict__ A,
                                                  const ushort_t* __restrict__ W,
                                                  const float* __restrict__ bias,
                                                  void* __restrict__ Cv,
                                                  int M, int Nout, int K, int KS,
                                                  int GN, int GM) {
    __shared__ ushort_t Ab[32768];   // [dbuf][kk-half][8192 elems]
    __shared__ ushort_t Bb[32768];
    int tid = threadIdx.x;
    int w  = tid >> 6, l = tid & 63;
    int li = l & 15,  g = l >> 4;
    int wm = w >> 2,  wn = w & 3;

    // ---- XCD-chunked decode ----
    int xcd = blockIdx.x & 7;
    int c   = blockIdx.x >> 3;
    int RN = GN >> 2, RM = GM >> 1;
    int rsz = RN * RM;
    int bz = c / rsz;
    int r  = c - bz * rsz;
    int bm = (xcd >> 2) * RM + r / RN;
    int bn = (xcd & 3) * RN + r % RN;

    // ---- staging source (pre-swizzled) ----
    int lc   = (l & 7) ^ (l >> 3);
    int sgr  = w * 32 + 2 * (l >> 3) + (lc >> 2);
    int colo = (lc & 3) * 8;
    const ushort_t* sA0 = A + (size_t)(bm * 256 + sgr) * K + bz * KS + colo;
    const ushort_t* sA1 = sA0 + (size_t)16 * K;
    const ushort_t* sB0 = W + (size_t)(bn * 256 + sgr) * K + bz * KS + colo;
    const ushort_t* sB1 = sB0 + (size_t)16 * K;

    // ---- read-side bases (bytes) ----
    uint_t chunkpos = (uint_t)(((((li & 1) << 2) + g) ^ (li >> 1)) << 4);
    uint_t aBase = (uint_t)(uintptr_t)(&Ab[0]) + (uint_t)(wm * 8192 + (li >> 1) * 128) + chunkpos;
    uint_t bBase = (uint_t)(uintptr_t)(&Bb[0]) + (uint_t)(wn * 4096 + (li >> 1) * 128) + chunkpos;

    f32x4 acc[8][4];
    #pragma unroll
    for (int i = 0; i < 8; i++)
        #pragma unroll
        for (int j = 0; j < 4; j++) acc[i][j] = (f32x4){0.f, 0.f, 0.f, 0.f};

    const int NT = KS >> 6;

    // ---- prologue: tile 0 -> dbuf 0; wait kk0 halves ----
    {
        ushort_t* dA = &Ab[0] + w * 1024;
        ushort_t* dB = &Bb[0] + w * 1024;
        gload_lds16(sA0,      dA);        gload_lds16(sA1,      dA + 512);
        gload_lds16(sB0,      dB);        gload_lds16(sB1,      dB + 512);
        gload_lds16(sA0 + 32, dA + 8192); gload_lds16(sA1 + 32, dA + 8192 + 512);
        gload_lds16(sB0 + 32, dB + 8192); gload_lds16(sB1 + 32, dB + 8192 + 512);
    }
    asm volatile("s_waitcnt vmcnt(4)" ::);
    SB0; BARR;

    for (int t = 0; t < NT; ++t) {
        int d = t & 1;
        bool pf = (t + 1 < NT);
        int kn = (t + 1) * 64;
        uint_t aAddr = aBase + (uint_t)(d * 32768);
        uint_t bAddr = bBase + (uint_t)(d * 32768);
        ushort_t* dA = &Ab[0] + (d ^ 1) * 16384 + w * 1024;
        ushort_t* dB = &Bb[0] + (d ^ 1) * 16384 + w * 1024;
        bf16x8 a0, a1, a2, a3, b0, b1, b2, b3;

        // ---- phase 0: qm0, kk0 (8 reads; stage A-h0 of t+1) ----
        DSR(a0, aAddr, "0");    DSR(a1, aAddr, "1024");
        DSR(a2, aAddr, "2048"); DSR(a3, aAddr, "3072");
        DSR(b0, bAddr, "0");    DSR(b1, bAddr, "1024");
        DSR(b2, bAddr, "2048"); DSR(b3, bAddr, "3072");
        if (pf) { gload_lds16(sA0 + kn, dA); gload_lds16(sA1 + kn, dA + 512); }
        SB0; BARR;
        LGKM(3); SB0;
        __builtin_amdgcn_s_setprio(1);
        GRP_QM0(0, b0)
        LGKM(2); SB0;
        GRP_QM0(1, b1)
        LGKM(1); SB0;
        GRP_QM0(2, b2)
        LGKM(0); SB0;
        GRP_QM0(3, b3)
        __builtin_amdgcn_s_setprio(0);
        SB0; BARR;

        // ---- phase 1: qm1, kk0 (4 reads; stage B-h0; vmcnt for t's kk1) ----
        DSR(a0, aAddr, "4096"); DSR(a1, aAddr, "5120");
        DSR(a2, aAddr, "6144"); DSR(a3, aAddr, "7168");
        if (pf) { gload_lds16(sB0 + kn, dB); gload_lds16(sB1 + kn, dB + 512); }
        SB0; BARR;
        LGKM(3); SB0;
        __builtin_amdgcn_s_setprio(1);
        GRP_QM1(4, a0)
        LGKM(2); SB0;
        GRP_QM1(5, a1)
        LGKM(1); SB0;
        GRP_QM1(6, a2)
        LGKM(0); SB0;
        GRP_QM1(7, a3)
        __builtin_amdgcn_s_setprio(0);
        if (pf) { asm volatile("s_waitcnt vmcnt(4)" ::); }
        else    { asm volatile("s_waitcnt vmcnt(0)" ::); }
        SB0; BARR;

        // ---- phase 2: qm0, kk1 (8 reads; stage A-h1) ----
        DSR(a0, aAddr, "16384"); DSR(a1, aAddr, "17408");
        DSR(a2, aAddr, "18432"); DSR(a3, aAddr, "19456");
        DSR(b0, bAddr, "16384"); DSR(b1, bAddr, "17408");
        DSR(b2, bAddr, "18432"); DSR(b3, bAddr, "19456");
        if (pf) { gload_lds16(sA0 + kn + 32, dA + 8192); gload_lds16(sA1 + kn + 32, dA + 8192 + 512); }
        SB0; BARR;
        LGKM(3); SB0;
        __builtin_amdgcn_s_setprio(1);
        GRP_QM0(0, b0)
        LGKM(2); SB0;
        GRP_QM0(1, b1)
        LGKM(1); SB0;
        GRP_QM0(2, b2)
        LGKM(0); SB0;
        GRP_QM0(3, b3)
        __builtin_amdgcn_s_setprio(0);
        SB0; BARR;

        // ---- phase 3: qm1, kk1 (4 reads; stage B-h1; vmcnt for t+1's kk0) ----
        DSR(a0, aAddr, "20480"); DSR(a1, aAddr, "21504");
        DSR(a2, aAddr, "22528"); DSR(a3, aAddr, "23552");
        if (pf) { gload_lds16(sB0 + kn + 32, dB + 8192); gload_lds16(sB1 + kn + 32, dB + 8192 + 512); }
        SB0; BARR;
        LGKM(3); SB0;
        __builtin_amdgcn_s_setprio(1);
        GRP_QM1(4, a0)
        LGKM(2); SB0;
        GRP_QM1(5, a1)
        LGKM(1); SB0;
        GRP_QM1(6, a2)
        LGKM(0); SB0;
        GRP_QM1(7, a3)
        __builtin_amdgcn_s_setprio(0);
        asm volatile("s_waitcnt vmcnt(4)" ::);
        SB0; BARR;
    }

    // ---- epilogue ----
    #pragma unroll
    for (int fm = 0; fm < 8; fm++) {
        #pragma unroll
        for (int fn = 0; fn < 4; fn++) {
            int nn = bn * 256 + wn * 64 + fn * 16 + li;
            int mB = bm * 256 + wm * 128 + (fm >> 2) * 64 + (fm & 3) * 16 + g * 4;
            if (MODE == 0) {
                int which = nn >> 10, col = nn & 1023;
                int h = col >> 6, dd = col & 63;
                int b = mB >> 11, n0 = mB & (Nmod - 1);
                ushort_t* C = (ushort_t*)Cv;
                if (which == 2) {
                    uint2 pk;
                    pk.x = (uint_t)f2bf(acc[fm][fn][0]) | ((uint_t)f2bf(acc[fm][fn][1]) << 16);
                    pk.y = (uint_t)f2bf(acc[fm][fn][2]) | ((uint_t)f2bf(acc[fm][fn][3]) << 16);
                    *(uint2*)(C + 8388608u + (((size_t)(b * NHmod + h)) * DHmod + dd) * Nmod + n0) = pk;
                } else {
                    #pragma unroll
                    for (int r2 = 0; r2 < 4; r2++) {
                        size_t idx = (size_t)which * 4194304u +
                                     (((size_t)(b * NHmod + h)) * Nmod + n0 + r2) * DHmod + dd;
                        C[idx] = f2bf(acc[fm][fn][r2]);
                    }
                }
            } else if (MODE == 2) {
                ushort_t* C = (ushort_t*)Cv;
                #pragma unroll
                for (int r2 = 0; r2 < 4; r2++)
                    C[(size_t)(mB + r2) * Nout + nn] = f2bf(gelu_f(acc[fm][fn][r2] + bias[nn]));
            } else {  // MODE 4
                ushort_t* P = (ushort_t*)Cv + (size_t)bz * M * Nout;
                #pragma unroll
                for (int r2 = 0; r2 < 4; r2++)
                    P[(size_t)(mB + r2) * Nout + nn] = f2bf(acc[fm][fn][r2]);
            }
        }
    }
}

// ---------------- 4-way bf16 split-K reduce + residual + LN (Wo path) ----------------
__global__ __launch_bounds__(256) void red_ln4_kernel(const ushort_t* __restrict__ p,
                                                      const float* __restrict__ x,
                                                      const float* __restrict__ bo,
                                                      const float* __restrict__ scale,
                                                      const float* __restrict__ shift,
                                                      float* __restrict__ x1,
                                                      ushort_t* __restrict__ h2) {
    int row = blockIdx.x;
    int t   = threadIdx.x;
    const size_t MD = (size_t)Mrows * Dmod;
    size_t i = (size_t)row * 256 + t;
    float4 xr = ((const float4*)(x + (size_t)row * Dmod))[t];
    float4 bb = ((const float4*)bo)[t];
    float4 v;
    v.x = xr.x + bb.x; v.y = xr.y + bb.y; v.z = xr.z + bb.z; v.w = xr.w + bb.w;
    #pragma unroll
    for (int z = 0; z < 4; z++) {
        uint2 pk = ((const uint2*)(p + (size_t)z * MD))[i];
        v.x += bf2f(pk.x & 0xffffu);
        v.y += bf2f(pk.x >> 16);
        v.z += bf2f(pk.y & 0xffffu);
        v.w += bf2f(pk.y >> 16);
    }
    ((float4*)(x1 + (size_t)row * Dmod))[t] = v;

    float s  = v.x + v.y + v.z + v.w;
    float s2 = v.x*v.x + v.y*v.y + v.z*v.z + v.w*v.w;
    __shared__ float rs[8], rs2[8];
    #pragma unroll
    for (int o = 32; o; o >>= 1) { s += __shfl_down(s, o); s2 += __shfl_down(s2, o); }
    int wave = t >> 6, lane = t & 63;
    if (lane == 0) { rs[wave] = s; rs2[wave] = s2; }
    __syncthreads();
    if (t == 0) {
        rs[0]  = rs[0] + rs[1] + rs[2] + rs[3];
        rs2[0] = rs2[0] + rs2[1] + rs2[2] + rs2[3];
    }
    __syncthreads();
    float mean = rs[0] * (1.0f / Dmod);
    float var  = rs2[0] * (1.0f / Dmod) - mean * mean;
    float rstd = rsqrtf(var + EPSLN);

    float4 sc = ((const float4*)scale)[t];
    float4 sh = ((const float4*)shift)[t];
    uint2 o;
    o.x = (uint_t)f2bf(sc.x * (v.x - mean) * rstd + sh.x) |
          ((uint_t)f2bf(sc.y * (v.y - mean) * rstd + sh.y) << 16);
    o.y = (uint_t)f2bf(sc.z * (v.z - mean) * rstd + sh.z) |
          ((uint_t)f2bf(sc.w * (v.w - mean) * rstd + sh.w) << 16);
    ((uint2*)(h2 + (size_t)row * Dmod))[t] = o;
}

// ---------------- 4-way bf16 split-K reduce + bias + residual (FFN-down) ----------------
__global__ __launch_bounds__(256) void red_out4_kernel(const ushort_t* __restrict__ p,
                                                       const float* __restrict__ x1,
                                                       const float* __restrict__ b2,
                                                       float* __restrict__ out) {
    const size_t MD4 = (size_t)Mrows * Dmod / 4;
    size_t i = (size_t)blockIdx.x * 256 + threadIdx.x;
    if (i >= MD4) return;
    float4 xr = ((const float4*)x1)[i];
    float4 bb = ((const float4*)b2)[i & 255];
    float4 v;
    v.x = xr.x + bb.x; v.y = xr.y + bb.y; v.z = xr.z + bb.z; v.w = xr.w + bb.w;
    #pragma unroll
    for (int z = 0; z < 4; z++) {
        uint2 pk = ((const uint2*)(p + (size_t)z * Mrows * Dmod))[i];
        v.x += bf2f(pk.x & 0xffffu);
        v.y += bf2f(pk.x >> 16);
        v.z += bf2f(pk.y & 0xffffu);
        v.w += bf2f(pk.y >> 16);
    }
    ((float4*)out)[i] = v;
}

// ---------------- Flash attention v4 (unchanged) ----------------
__global__ __launch_bounds__(256) void fattn_kernel(const ushort_t* __restrict__ Q,
                                                    const ushort_t* __restrict__ K,
                                                    const ushort_t* __restrict__ VT,
                                                    ushort_t* __restrict__ O) {
    int bid = blockIdx.x;
    int xcd = bid & 7;
    int j   = bid >> 3;
    int bh  = xcd * 4 + (j & 3);
    int qt  = 31 - (j >> 2);
    int b   = bh >> 4, hh = bh & 15;
    int w    = threadIdx.x >> 6;
    int lane = threadIdx.x & 63;
    int li   = lane & 15;
    int g    = lane >> 4;

    __shared__ ushort_t Klds[2][4096];
    __shared__ ushort_t Vlds[2][4096];
    __shared__ ushort_t Plds[4][16][72];

    int q0 = qt * 64 + w * 16;
    int q  = q0 + li;

    const ushort_t* Qb = Q  + (size_t)bh * Nmod * DHmod;
    const ushort_t* Kb = K  + (size_t)bh * Nmod * DHmod;
    const ushort_t* Vb = VT + (size_t)bh * DHmod * Nmod;

    bf16x8 qf[2];
    #pragma unroll
    for (int c = 0; c < 2; c++)
        qf[c] = *(const bf16x8*)(Qb + (size_t)q * DHmod + c * 32 + g * 8);

    f32x4 po[4];
    #pragma unroll
    for (int mt = 0; mt < 4; mt++) po[mt] = (f32x4){0.f, 0.f, 0.f, 0.f};
    float l = 0.f;

    const int ntiles = qt + 1;

    int r_sub = lane >> 3;
    int cc    = ((lane & 7) ^ (r_sub & 7)) * 8;

    int swz  = (li & 7) * 8;
    int roff = li * 64;
    int c0k  = (g * 8) ^ swz;
    int c1k  = (32 + g * 8) ^ swz;

    auto stage = [&](int buf, int kt) {
        int k0 = kt * 64;
        #pragma unroll
        for (int i2 = 0; i2 < 2; i2++) {
            int i   = w * 2 + i2;
            int row = i * 8 + r_sub;
            gload_lds16(Kb + (size_t)(k0 + row) * DHmod + cc, &Klds[buf][i * 512]);
            gload_lds16(Vb + (size_t)row * Nmod + k0 + cc,    &Vlds[buf][i * 512]);
        }
    };

    stage(0, 0);

    for (int kt = 0; kt < ntiles; ++kt) {
        __syncthreads();
        if (kt + 1 < ntiles) stage((kt + 1) & 1, kt + 1);
        int cur = kt & 1;
        int k0  = kt * 64;

        f32x4 s[4];
        __builtin_amdgcn_s_setprio(1);
        #pragma unroll
        for (int mt = 0; mt < 4; mt++) {
            bf16x8 kf0 = *(const bf16x8*)&Klds[cur][mt * 1024 + roff + c0k];
            bf16x8 kf1 = *(const bf16x8*)&Klds[cur][mt * 1024 + roff + c1k];
            s[mt] = (f32x4){0.f, 0.f, 0.f, 0.f};
            s[mt] = MFMA16x16x32(kf0, qf[0], s[mt]);
            s[mt] = MFMA16x16x32(kf1, qf[1], s[mt]);
        }
        __builtin_amdgcn_s_setprio(0);

        if (kt == qt) {
            #pragma unroll
            for (int mt = 0; mt < 4; mt++)
                #pragma unroll
                for (int r = 0; r < 4; r++)
                    if (k0 + mt * 16 + g * 4 + r > q) s[mt][r] = -INFINITY;
        }
        float ptile = 0.f;
        #pragma unroll
        for (int mt = 0; mt < 4; mt++) {
            float p0 = __expf(s[mt][0]);
            float p1 = __expf(s[mt][1]);
            float p2 = __expf(s[mt][2]);
            float p3 = __expf(s[mt][3]);
            ptile += (p0 + p1) + (p2 + p3);
            uint2 pk;
            pk.x = (uint_t)f2bf(p0) | ((uint_t)f2bf(p1) << 16);
            pk.y = (uint_t)f2bf(p2) | ((uint_t)f2bf(p3) << 16);
            *(uint2*)&Plds[w][li][mt * 16 + g * 4] = pk;
        }
        l += ptile;

        asm volatile("" ::: "memory");

        bf16x8 pf0 = *(const bf16x8*)&Plds[w][li][g * 8];
        bf16x8 pf1 = *(const bf16x8*)&Plds[w][li][32 + g * 8];
        __builtin_amdgcn_s_setprio(1);
        #pragma unroll
        for (int mt = 0; mt < 4; mt++) {
            bf16x8 vf0 = *(const bf16x8*)&Vlds[cur][mt * 1024 + roff + c0k];
            bf16x8 vf1 = *(const bf16x8*)&Vlds[cur][mt * 1024 + roff + c1k];
            po[mt] = MFMA16x16x32(vf0, pf0, po[mt]);
            po[mt] = MFMA16x16x32(vf1, pf1, po[mt]);
        }
        __builtin_amdgcn_s_setprio(0);
        asm volatile("" ::: "memory");
    }

    l += __shfl_xor(l, 16);
    l += __shfl_xor(l, 32);
    float inv = 1.0f / l;
    ushort_t* Orow = O + ((size_t)(b * Nmod + q)) * Dmod + hh * DHmod;
    #pragma unroll
    for (int mt = 0; mt < 4; mt++) {
        uint2 pk;
        pk.x = (uint_t)f2bf(po[mt][0] * inv) | ((uint_t)f2bf(po[mt][1] * inv) << 16);
        pk.y = (uint_t)f2bf(po[mt][2] * inv) | ((uint_t)f2bf(po[mt][3] * inv) << 16);
        *(uint2*)(Orow + mt * 16 + g * 4) = pk;
    }
}

// ---------------- launcher ----------------
extern "C" void kernel_launch(void* const* d_in, const int* in_sizes, int n_in,
                              void* d_out, int out_size, void* d_ws, size_t ws_size,
                              hipStream_t stream) {
    const float* x    = (const float*)d_in[0];
    const float* Wq   = (const float*)d_in[1];
    const float* Wk   = (const float*)d_in[2];
    const float* Wv   = (const float*)d_in[3];
    const float* Wo   = (const float*)d_in[4];
    const float* bo   = (const float*)d_in[5];
    const float* ln1s = (const float*)d_in[6];
    const float* ln1b = (const float*)d_in[7];
    const float* ln2s = (const float*)d_in[8];
    const float* ln2b = (const float*)d_in[9];
    const float* W1   = (const float*)d_in[10];
    const float* b1   = (const float*)d_in[11];
    const float* W2   = (const float*)d_in[12];
    const float* b2   = (const float*)d_in[13];
    float* out = (float*)d_out;
    char*  wsb = (char*)d_ws;

    // workspace layout (112 MB)
    ushort_t* h_bf  = (ushort_t*)wsb;                  // 8MB  LN1 out; reused as att
    ushort_t* qb    = (ushort_t*)(wsb + (8u  << 20));  // 8MB  Q
    ushort_t* kb    = qb + 4194304;                    // 8MB  K
    ushort_t* vtb   = qb + 8388608;                    // 8MB  V^T
    float*    x1    = (float*)(wsb + (32u << 20));     // 16MB x + attn
    ushort_t* h2_bf = (ushort_t*)(wsb + (48u << 20));  // 8MB  LN2 out
    ushort_t* g_bf  = (ushort_t*)(wsb + (56u << 20));  // 32MB FFN hidden
    ushort_t* wqkv  = (ushort_t*)(wsb + (88u << 20));  // 6MB
    ushort_t* wo_b  = (ushort_t*)(wsb + (94u << 20));  // 2MB
    ushort_t* w1_b  = (ushort_t*)(wsb + (96u << 20));  // 8MB
    ushort_t* w2_b  = (ushort_t*)(wsb + (104u << 20)); // 8MB
    ushort_t* att   = h_bf;
    // split-K partial regions (4 x 8MB bf16 each):
    ushort_t* pWoB = (ushort_t*)(wsb + (56u << 20));   // g_bf region: consumed by red_ln4 BEFORE FFN-up writes g
    ushort_t* pFd  = (ushort_t*)wsb;                   // h/q/k/v region: free after Wo GEMM

    cvt_kernel<<<6144, 256, 0, stream>>>(Wq, Wk, Wv, Wo, W1, W2, wqkv, wo_b, w1_b, w2_b);
    ln_bf_kernel<<<Mrows, 256, 0, stream>>>(x, ln1s, ln1b, h_bf);
    // QKV: 8-phase 256x256, GN=12, GM=16 -> 192 blocks
    gemm256<0><<<192, 512, 0, stream>>>(h_bf, wqkv, nullptr, qb, Mrows, 3072, Dmod, Dmod, 12, 16);
    fattn_kernel<<<1024, 256, 0, stream>>>(qb, kb, vtb, att);
    // Wo: 8-phase 256x256 split-K=4 (bf16 partials), GN=4, GM=16, z=4 -> 256 blocks
    gemm256<4><<<256, 512, 0, stream>>>(att, wo_b, nullptr, pWoB, Mrows, Dmod, Dmod, Dmod / 4, 4, 16);
    // reduce 4 partials + bias + resid + LN2 fused
    red_ln4_kernel<<<Mrows, 256, 0, stream>>>(pWoB, x, bo, ln2s, ln2b, x1, h2_bf);
    // FFN up: 8-phase 256x256, GN=16, GM=16 -> 256 blocks
    gemm256<2><<<256, 512, 0, stream>>>(h2_bf, w1_b, b1, g_bf, Mrows, FF, Dmod, Dmod, 16, 16);
    // FFN down: 8-phase 256x256, split-K=4 (bf16 partials), GN=4, GM=16 -> 256 blocks
    gemm256<4><<<256, 512, 0, stream>>>(g_bf, w2_b, nullptr, pFd, Mrows, Dmod, FF, FF / 4, 4, 16);
    red_out4_kernel<<<(Mrows * Dmod / 4 + 255) / 256, 256, 0, stream>>>(pFd, x1, b2, out);
}

// Round 17
// 219.412 us; speedup vs baseline: 1.0072x; 1.0072x over previous
//
#include <hip/hip_runtime.h>
#include <hip/hip_bf16.h>
#include <math.h>

// ---------------- problem constants ----------------
#define Dmod   1024
#define NHmod  16
#define DHmod  64
#define Bmod   2
#define Nmod   2048
#define Mrows  (Bmod * Nmod)        // 4096
#define FF     (4 * Dmod)           // 4096
#define EPSLN  1e-5f

typedef __attribute__((ext_vector_type(8))) short bf16x8;
typedef __attribute__((ext_vector_type(4))) float f32x4;
typedef unsigned short ushort_t;
typedef unsigned int uint_t;

#define MFMA16x16x32(a, b, c) __builtin_amdgcn_mfma_f32_16x16x32_bf16((a), (b), (c), 0, 0, 0)

#define AS1 __attribute__((address_space(1)))
#define AS3 __attribute__((address_space(3)))

__device__ __forceinline__ void gload_lds16(const ushort_t* g, ushort_t* l) {
    __builtin_amdgcn_global_load_lds((const AS1 uint_t*)(const void*)g,
                                     (AS3 uint_t*)(void*)l, 16, 0, 0);
}

__device__ __forceinline__ ushort_t f2bf(float f) {
    union { float f; uint_t u; } v; v.f = f;
    uint_t r = v.u + 0x7FFFu + ((v.u >> 16) & 1u);   // RNE
    return (ushort_t)(r >> 16);
}

__device__ __forceinline__ float bf2f(uint_t u) {
    union { float f; uint_t u; } v; v.u = u << 16;
    return v.f;
}

// ---------------- fused fp32->bf16 weight conversion ----------------
__global__ __launch_bounds__(256) void cvt_kernel(const float* __restrict__ Wq, const float* __restrict__ Wk,
                                                  const float* __restrict__ Wv, const float* __restrict__ Wo,
                                                  const float* __restrict__ W1, const float* __restrict__ W2,
                                                  ushort_t* __restrict__ qkv, ushort_t* __restrict__ wo,
                                                  ushort_t* __restrict__ w1, ushort_t* __restrict__ w2) {
    int u = blockIdx.x * 256 + threadIdx.x;
    const float* src; ushort_t* dst; int i;
    float scale = 1.0f;
    if (u < 393216) {
        if (u < 131072)      { src = Wq; dst = qkv;           i = u; scale = 0.125f; }
        else if (u < 262144) { src = Wk; dst = qkv + 1048576; i = u - 131072; }
        else                 { src = Wv; dst = qkv + 2097152; i = u - 262144; }
    } else if (u < 524288)   { src = Wo; dst = wo; i = u - 393216; }
    else if (u < 1048576)    { src = W1; dst = w1; i = u - 524288; }
    else                     { src = W2; dst = w2; i = u - 1048576; }
    float4 a = ((const float4*)src)[2 * i];
    float4 b = ((const float4*)src)[2 * i + 1];
    uint4 o;
    o.x = (uint_t)f2bf(a.x * scale) | ((uint_t)f2bf(a.y * scale) << 16);
    o.y = (uint_t)f2bf(a.z * scale) | ((uint_t)f2bf(a.w * scale) << 16);
    o.z = (uint_t)f2bf(b.x * scale) | ((uint_t)f2bf(b.y * scale) << 16);
    o.w = (uint_t)f2bf(b.z * scale) | ((uint_t)f2bf(b.w * scale) << 16);
    ((uint4*)dst)[i] = o;
}

// ---------------- LayerNorm -> bf16 out ----------------
__global__ __launch_bounds__(256) void ln_bf_kernel(const float* __restrict__ x,
                                                    const float* __restrict__ scale,
                                                    const float* __restrict__ shift,
                                                    ushort_t* __restrict__ out) {
    int row = blockIdx.x;
    const float4* xr = (const float4*)(x + (size_t)row * Dmod);
    float4 v = xr[threadIdx.x];
    float s  = v.x + v.y + v.z + v.w;
    float s2 = v.x*v.x + v.y*v.y + v.z*v.z + v.w*v.w;

    __shared__ float rs[8], rs2[8];
    #pragma unroll
    for (int o = 32; o; o >>= 1) { s += __shfl_down(s, o); s2 += __shfl_down(s2, o); }
    int wave = threadIdx.x >> 6, lane = threadIdx.x & 63;
    if (lane == 0) { rs[wave] = s; rs2[wave] = s2; }
    __syncthreads();
    if (threadIdx.x == 0) {
        rs[0]  = rs[0] + rs[1] + rs[2] + rs[3];
        rs2[0] = rs2[0] + rs2[1] + rs2[2] + rs2[3];
    }
    __syncthreads();
    float mean = rs[0] * (1.0f / Dmod);
    float var  = rs2[0] * (1.0f / Dmod) - mean * mean;
    float rstd = rsqrtf(var + EPSLN);

    float4 sc = ((const float4*)scale)[threadIdx.x];
    float4 sh = ((const float4*)shift)[threadIdx.x];
    uint2 o;
    o.x = (uint_t)f2bf(sc.x * (v.x - mean) * rstd + sh.x) |
          ((uint_t)f2bf(sc.y * (v.y - mean) * rstd + sh.y) << 16);
    o.y = (uint_t)f2bf(sc.z * (v.z - mean) * rstd + sh.z) |
          ((uint_t)f2bf(sc.w * (v.w - mean) * rstd + sh.w) << 16);
    ((uint2*)(out + (size_t)row * Dmod))[threadIdx.x] = o;
}

// ---------------- GELU via sigmoid identity ----------------
__device__ __forceinline__ float gelu_f(float x) {
    const float c = 0.7978845608028654f;     // sqrt(2/pi)
    float u = c * (x + 0.044715f * x * x * x);
    return x / (1.0f + __expf(-2.0f * u));
}

// ================ 256x256 BK64 8-wave GEMM, 1-barrier-per-tile ================
// Key insight vs round 15/16: all 4 phases consume a tile fully resident at
// tile start, so intra-tile barriers protect nothing.  Structure per K-tile:
//   p0: 8 ds_read (kk0) + issue ALL 8 stage loads of t+1 -> counted-lgkm MFMA
//   p1: 4 ds_read -> counted-lgkm MFMA      (per-wave waits, no barriers)
//   p2: 8 ds_read (kk1) -> ...   p3: 4 ds_read -> ...
//   vmcnt(0) [stages ~4 phases old -> drain ~free]; s_barrier.
// Hazards: stage(t+1) writes d^1 whose prior readers (tile t-1) completed
// via p3's lgkm(0) before the t-1 tile-end barrier.  Cross-wave visibility
// of staged data: tile-end vmcnt(0)+barrier.  (T4 flight-depth, T5, T18.)
// MODE 0: QKV scatter; 2: +bias GELU bf16; 4: bf16 split-K partial.
#define DSR(D, A, OFF) asm volatile("ds_read_b128 %0, %1 offset:" OFF : "=v"(D) : "v"(A))
#define SB0 __builtin_amdgcn_sched_barrier(0)
#define BARR __builtin_amdgcn_s_barrier()
#define LGKM(N) asm volatile("s_waitcnt lgkmcnt(" #N ")" ::)

#define GRP_QM0(J, B) \
  acc[0][J]=MFMA16x16x32(a0,B,acc[0][J]); acc[1][J]=MFMA16x16x32(a1,B,acc[1][J]); \
  acc[2][J]=MFMA16x16x32(a2,B,acc[2][J]); acc[3][J]=MFMA16x16x32(a3,B,acc[3][J]);
#define GRP_QM1(I, A) \
  acc[I][0]=MFMA16x16x32(A,b0,acc[I][0]); acc[I][1]=MFMA16x16x32(A,b1,acc[I][1]); \
  acc[I][2]=MFMA16x16x32(A,b2,acc[I][2]); acc[I][3]=MFMA16x16x32(A,b3,acc[I][3]);

template <int MODE>
__global__ __launch_bounds__(512, 2) void gemm256(const ushort_t* __restrict__ A,
                                                  const ushort_t* __restrict__ W,
                                                  const float* __restrict__ bias,
                                                  void* __restrict__ Cv,
                                                  int M, int Nout, int K, int KS,
                                                  int GN, int GM) {
    __shared__ ushort_t Ab[32768];   // [dbuf][kk-half][8192 elems]
    __shared__ ushort_t Bb[32768];
    int tid = threadIdx.x;
    int w  = tid >> 6, l = tid & 63;
    int li = l & 15,  g = l >> 4;
    int wm = w >> 2,  wn = w & 3;

    // ---- XCD-chunked decode ----
    int xcd = blockIdx.x & 7;
    int c   = blockIdx.x >> 3;
    int RN = GN >> 2, RM = GM >> 1;
    int rsz = RN * RM;
    int bz = c / rsz;
    int r  = c - bz * rsz;
    int bm = (xcd >> 2) * RM + r / RN;
    int bn = (xcd & 3) * RN + r % RN;

    // ---- staging source (pre-swizzled) ----
    int lc   = (l & 7) ^ (l >> 3);
    int sgr  = w * 32 + 2 * (l >> 3) + (lc >> 2);
    int colo = (lc & 3) * 8;
    const ushort_t* sA0 = A + (size_t)(bm * 256 + sgr) * K + bz * KS + colo;
    const ushort_t* sA1 = sA0 + (size_t)16 * K;
    const ushort_t* sB0 = W + (size_t)(bn * 256 + sgr) * K + bz * KS + colo;
    const ushort_t* sB1 = sB0 + (size_t)16 * K;

    // ---- read-side bases (bytes) ----
    uint_t chunkpos = (uint_t)(((((li & 1) << 2) + g) ^ (li >> 1)) << 4);
    uint_t aBase = (uint_t)(uintptr_t)(&Ab[0]) + (uint_t)(wm * 8192 + (li >> 1) * 128) + chunkpos;
    uint_t bBase = (uint_t)(uintptr_t)(&Bb[0]) + (uint_t)(wn * 4096 + (li >> 1) * 128) + chunkpos;

    f32x4 acc[8][4];
    #pragma unroll
    for (int i = 0; i < 8; i++)
        #pragma unroll
        for (int j = 0; j < 4; j++) acc[i][j] = (f32x4){0.f, 0.f, 0.f, 0.f};

    const int NT = KS >> 6;

    auto stage_all = [&](int dst, int t) {
        int kn = t * 64;
        ushort_t* dA = &Ab[0] + dst * 16384 + w * 1024;
        ushort_t* dB = &Bb[0] + dst * 16384 + w * 1024;
        gload_lds16(sA0 + kn,      dA);        gload_lds16(sA1 + kn,      dA + 512);
        gload_lds16(sB0 + kn,      dB);        gload_lds16(sB1 + kn,      dB + 512);
        gload_lds16(sA0 + kn + 32, dA + 8192); gload_lds16(sA1 + kn + 32, dA + 8192 + 512);
        gload_lds16(sB0 + kn + 32, dB + 8192); gload_lds16(sB1 + kn + 32, dB + 8192 + 512);
    };

    // ---- prologue: stage tile 0 fully, drain, barrier ----
    stage_all(0, 0);
    asm volatile("s_waitcnt vmcnt(0)" ::);
    SB0; BARR;

    for (int t = 0; t < NT; ++t) {
        int d = t & 1;
        uint_t aAddr = aBase + (uint_t)(d * 32768);
        uint_t bAddr = bBase + (uint_t)(d * 32768);
        bf16x8 a0, a1, a2, a3, b0, b1, b2, b3;

        // ---- phase 0: qm0, kk0 (8 reads; issue ALL stages of t+1) ----
        DSR(a0, aAddr, "0");    DSR(a1, aAddr, "1024");
        DSR(a2, aAddr, "2048"); DSR(a3, aAddr, "3072");
        DSR(b0, bAddr, "0");    DSR(b1, bAddr, "1024");
        DSR(b2, bAddr, "2048"); DSR(b3, bAddr, "3072");
        if (t + 1 < NT) stage_all(d ^ 1, t + 1);
        SB0;
        LGKM(3); SB0;
        __builtin_amdgcn_s_setprio(1);
        GRP_QM0(0, b0)
        LGKM(2); SB0;
        GRP_QM0(1, b1)
        LGKM(1); SB0;
        GRP_QM0(2, b2)
        LGKM(0); SB0;
        GRP_QM0(3, b3)
        __builtin_amdgcn_s_setprio(0);

        // ---- phase 1: qm1, kk0 (4 reads) ----
        DSR(a0, aAddr, "4096"); DSR(a1, aAddr, "5120");
        DSR(a2, aAddr, "6144"); DSR(a3, aAddr, "7168");
        SB0;
        LGKM(3); SB0;
        __builtin_amdgcn_s_setprio(1);
        GRP_QM1(4, a0)
        LGKM(2); SB0;
        GRP_QM1(5, a1)
        LGKM(1); SB0;
        GRP_QM1(6, a2)
        LGKM(0); SB0;
        GRP_QM1(7, a3)
        __builtin_amdgcn_s_setprio(0);

        // ---- phase 2: qm0, kk1 (8 reads) ----
        DSR(a0, aAddr, "16384"); DSR(a1, aAddr, "17408");
        DSR(a2, aAddr, "18432"); DSR(a3, aAddr, "19456");
        DSR(b0, bAddr, "16384"); DSR(b1, bAddr, "17408");
        DSR(b2, bAddr, "18432"); DSR(b3, bAddr, "19456");
        SB0;
        LGKM(3); SB0;
        __builtin_amdgcn_s_setprio(1);
        GRP_QM0(0, b0)
        LGKM(2); SB0;
        GRP_QM0(1, b1)
        LGKM(1); SB0;
        GRP_QM0(2, b2)
        LGKM(0); SB0;
        GRP_QM0(3, b3)
        __builtin_amdgcn_s_setprio(0);

        // ---- phase 3: qm1, kk1 (4 reads) ----
        DSR(a0, aAddr, "20480"); DSR(a1, aAddr, "21504");
        DSR(a2, aAddr, "22528"); DSR(a3, aAddr, "23552");
        SB0;
        LGKM(3); SB0;
        __builtin_amdgcn_s_setprio(1);
        GRP_QM1(4, a0)
        LGKM(2); SB0;
        GRP_QM1(5, a1)
        LGKM(1); SB0;
        GRP_QM1(6, a2)
        LGKM(0); SB0;
        GRP_QM1(7, a3)
        __builtin_amdgcn_s_setprio(0);

        // ---- tile end: stages of t+1 (~4 phases old) drained; one barrier ----
        asm volatile("s_waitcnt vmcnt(0)" ::);
        SB0; BARR;
    }

    // ---- epilogue ----
    #pragma unroll
    for (int fm = 0; fm < 8; fm++) {
        #pragma unroll
        for (int fn = 0; fn < 4; fn++) {
            int nn = bn * 256 + wn * 64 + fn * 16 + li;
            int mB = bm * 256 + wm * 128 + (fm >> 2) * 64 + (fm & 3) * 16 + g * 4;
            if (MODE == 0) {
                int which = nn >> 10, col = nn & 1023;
                int h = col >> 6, dd = col & 63;
                int b = mB >> 11, n0 = mB & (Nmod - 1);
                ushort_t* C = (ushort_t*)Cv;
                if (which == 2) {
                    uint2 pk;
                    pk.x = (uint_t)f2bf(acc[fm][fn][0]) | ((uint_t)f2bf(acc[fm][fn][1]) << 16);
                    pk.y = (uint_t)f2bf(acc[fm][fn][2]) | ((uint_t)f2bf(acc[fm][fn][3]) << 16);
                    *(uint2*)(C + 8388608u + (((size_t)(b * NHmod + h)) * DHmod + dd) * Nmod + n0) = pk;
                } else {
                    #pragma unroll
                    for (int r2 = 0; r2 < 4; r2++) {
                        size_t idx = (size_t)which * 4194304u +
                                     (((size_t)(b * NHmod + h)) * Nmod + n0 + r2) * DHmod + dd;
                        C[idx] = f2bf(acc[fm][fn][r2]);
                    }
                }
            } else if (MODE == 2) {
                ushort_t* C = (ushort_t*)Cv;
                #pragma unroll
                for (int r2 = 0; r2 < 4; r2++)
                    C[(size_t)(mB + r2) * Nout + nn] = f2bf(gelu_f(acc[fm][fn][r2] + bias[nn]));
            } else {  // MODE 4
                ushort_t* P = (ushort_t*)Cv + (size_t)bz * M * Nout;
                #pragma unroll
                for (int r2 = 0; r2 < 4; r2++)
                    P[(size_t)(mB + r2) * Nout + nn] = f2bf(acc[fm][fn][r2]);
            }
        }
    }
}

// ---------------- 4-way bf16 split-K reduce + residual + LN (Wo path) ----------------
__global__ __launch_bounds__(256) void red_ln4_kernel(const ushort_t* __restrict__ p,
                                                      const float* __restrict__ x,
                                                      const float* __restrict__ bo,
                                                      const float* __restrict__ scale,
                                                      const float* __restrict__ shift,
                                                      float* __restrict__ x1,
                                                      ushort_t* __restrict__ h2) {
    int row = blockIdx.x;
    int t   = threadIdx.x;
    const size_t MD = (size_t)Mrows * Dmod;
    size_t i = (size_t)row * 256 + t;
    float4 xr = ((const float4*)(x + (size_t)row * Dmod))[t];
    float4 bb = ((const float4*)bo)[t];
    float4 v;
    v.x = xr.x + bb.x; v.y = xr.y + bb.y; v.z = xr.z + bb.z; v.w = xr.w + bb.w;
    #pragma unroll
    for (int z = 0; z < 4; z++) {
        uint2 pk = ((const uint2*)(p + (size_t)z * MD))[i];
        v.x += bf2f(pk.x & 0xffffu);
        v.y += bf2f(pk.x >> 16);
        v.z += bf2f(pk.y & 0xffffu);
        v.w += bf2f(pk.y >> 16);
    }
    ((float4*)(x1 + (size_t)row * Dmod))[t] = v;

    float s  = v.x + v.y + v.z + v.w;
    float s2 = v.x*v.x + v.y*v.y + v.z*v.z + v.w*v.w;
    __shared__ float rs[8], rs2[8];
    #pragma unroll
    for (int o = 32; o; o >>= 1) { s += __shfl_down(s, o); s2 += __shfl_down(s2, o); }
    int wave = t >> 6, lane = t & 63;
    if (lane == 0) { rs[wave] = s; rs2[wave] = s2; }
    __syncthreads();
    if (t == 0) {
        rs[0]  = rs[0] + rs[1] + rs[2] + rs[3];
        rs2[0] = rs2[0] + rs2[1] + rs2[2] + rs2[3];
    }
    __syncthreads();
    float mean = rs[0] * (1.0f / Dmod);
    float var  = rs2[0] * (1.0f / Dmod) - mean * mean;
    float rstd = rsqrtf(var + EPSLN);

    float4 sc = ((const float4*)scale)[t];
    float4 sh = ((const float4*)shift)[t];
    uint2 o;
    o.x = (uint_t)f2bf(sc.x * (v.x - mean) * rstd + sh.x) |
          ((uint_t)f2bf(sc.y * (v.y - mean) * rstd + sh.y) << 16);
    o.y = (uint_t)f2bf(sc.z * (v.z - mean) * rstd + sh.z) |
          ((uint_t)f2bf(sc.w * (v.w - mean) * rstd + sh.w) << 16);
    ((uint2*)(h2 + (size_t)row * Dmod))[t] = o;
}

// ---------------- 4-way bf16 split-K reduce + bias + residual (FFN-down) ----------------
__global__ __launch_bounds__(256) void red_out4_kernel(const ushort_t* __restrict__ p,
                                                       const float* __restrict__ x1,
                                                       const float* __restrict__ b2,
                                                       float* __restrict__ out) {
    const size_t MD4 = (size_t)Mrows * Dmod / 4;
    size_t i = (size_t)blockIdx.x * 256 + threadIdx.x;
    if (i >= MD4) return;
    float4 xr = ((const float4*)x1)[i];
    float4 bb = ((const float4*)b2)[i & 255];
    float4 v;
    v.x = xr.x + bb.x; v.y = xr.y + bb.y; v.z = xr.z + bb.z; v.w = xr.w + bb.w;
    #pragma unroll
    for (int z = 0; z < 4; z++) {
        uint2 pk = ((const uint2*)(p + (size_t)z * Mrows * Dmod))[i];
        v.x += bf2f(pk.x & 0xffffu);
        v.y += bf2f(pk.x >> 16);
        v.z += bf2f(pk.y & 0xffffu);
        v.w += bf2f(pk.y >> 16);
    }
    ((float4*)out)[i] = v;
}

// ---------------- Flash attention v4 (unchanged) ----------------
__global__ __launch_bounds__(256) void fattn_kernel(const ushort_t* __restrict__ Q,
                                                    const ushort_t* __restrict__ K,
                                                    const ushort_t* __restrict__ VT,
                                                    ushort_t* __restrict__ O) {
    int bid = blockIdx.x;
    int xcd = bid & 7;
    int j   = bid >> 3;
    int bh  = xcd * 4 + (j & 3);
    int qt  = 31 - (j >> 2);
    int b   = bh >> 4, hh = bh & 15;
    int w    = threadIdx.x >> 6;
    int lane = threadIdx.x & 63;
    int li   = lane & 15;
    int g    = lane >> 4;

    __shared__ ushort_t Klds[2][4096];
    __shared__ ushort_t Vlds[2][4096];
    __shared__ ushort_t Plds[4][16][72];

    int q0 = qt * 64 + w * 16;
    int q  = q0 + li;

    const ushort_t* Qb = Q  + (size_t)bh * Nmod * DHmod;
    const ushort_t* Kb = K  + (size_t)bh * Nmod * DHmod;
    const ushort_t* Vb = VT + (size_t)bh * DHmod * Nmod;

    bf16x8 qf[2];
    #pragma unroll
    for (int c = 0; c < 2; c++)
        qf[c] = *(const bf16x8*)(Qb + (size_t)q * DHmod + c * 32 + g * 8);

    f32x4 po[4];
    #pragma unroll
    for (int mt = 0; mt < 4; mt++) po[mt] = (f32x4){0.f, 0.f, 0.f, 0.f};
    float l = 0.f;

    const int ntiles = qt + 1;

    int r_sub = lane >> 3;
    int cc    = ((lane & 7) ^ (r_sub & 7)) * 8;

    int swz  = (li & 7) * 8;
    int roff = li * 64;
    int c0k  = (g * 8) ^ swz;
    int c1k  = (32 + g * 8) ^ swz;

    auto stage = [&](int buf, int kt) {
        int k0 = kt * 64;
        #pragma unroll
        for (int i2 = 0; i2 < 2; i2++) {
            int i   = w * 2 + i2;
            int row = i * 8 + r_sub;
            gload_lds16(Kb + (size_t)(k0 + row) * DHmod + cc, &Klds[buf][i * 512]);
            gload_lds16(Vb + (size_t)row * Nmod + k0 + cc,    &Vlds[buf][i * 512]);
        }
    };

    stage(0, 0);

    for (int kt = 0; kt < ntiles; ++kt) {
        __syncthreads();
        if (kt + 1 < ntiles) stage((kt + 1) & 1, kt + 1);
        int cur = kt & 1;
        int k0  = kt * 64;

        f32x4 s[4];
        __builtin_amdgcn_s_setprio(1);
        #pragma unroll
        for (int mt = 0; mt < 4; mt++) {
            bf16x8 kf0 = *(const bf16x8*)&Klds[cur][mt * 1024 + roff + c0k];
            bf16x8 kf1 = *(const bf16x8*)&Klds[cur][mt * 1024 + roff + c1k];
            s[mt] = (f32x4){0.f, 0.f, 0.f, 0.f};
            s[mt] = MFMA16x16x32(kf0, qf[0], s[mt]);
            s[mt] = MFMA16x16x32(kf1, qf[1], s[mt]);
        }
        __builtin_amdgcn_s_setprio(0);

        if (kt == qt) {
            #pragma unroll
            for (int mt = 0; mt < 4; mt++)
                #pragma unroll
                for (int r = 0; r < 4; r++)
                    if (k0 + mt * 16 + g * 4 + r > q) s[mt][r] = -INFINITY;
        }
        float ptile = 0.f;
        #pragma unroll
        for (int mt = 0; mt < 4; mt++) {
            float p0 = __expf(s[mt][0]);
            float p1 = __expf(s[mt][1]);
            float p2 = __expf(s[mt][2]);
            float p3 = __expf(s[mt][3]);
            ptile += (p0 + p1) + (p2 + p3);
            uint2 pk;
            pk.x = (uint_t)f2bf(p0) | ((uint_t)f2bf(p1) << 16);
            pk.y = (uint_t)f2bf(p2) | ((uint_t)f2bf(p3) << 16);
            *(uint2*)&Plds[w][li][mt * 16 + g * 4] = pk;
        }
        l += ptile;

        asm volatile("" ::: "memory");

        bf16x8 pf0 = *(const bf16x8*)&Plds[w][li][g * 8];
        bf16x8 pf1 = *(const bf16x8*)&Plds[w][li][32 + g * 8];
        __builtin_amdgcn_s_setprio(1);
        #pragma unroll
        for (int mt = 0; mt < 4; mt++) {
            bf16x8 vf0 = *(const bf16x8*)&Vlds[cur][mt * 1024 + roff + c0k];
            bf16x8 vf1 = *(const bf16x8*)&Vlds[cur][mt * 1024 + roff + c1k];
            po[mt] = MFMA16x16x32(vf0, pf0, po[mt]);
            po[mt] = MFMA16x16x32(vf1, pf1, po[mt]);
        }
        __builtin_amdgcn_s_setprio(0);
        asm volatile("" ::: "memory");
    }

    l += __shfl_xor(l, 16);
    l += __shfl_xor(l, 32);
    float inv = 1.0f / l;
    ushort_t* Orow = O + ((size_t)(b * Nmod + q)) * Dmod + hh * DHmod;
    #pragma unroll
    for (int mt = 0; mt < 4; mt++) {
        uint2 pk;
        pk.x = (uint_t)f2bf(po[mt][0] * inv) | ((uint_t)f2bf(po[mt][1] * inv) << 16);
        pk.y = (uint_t)f2bf(po[mt][2] * inv) | ((uint_t)f2bf(po[mt][3] * inv) << 16);
        *(uint2*)(Orow + mt * 16 + g * 4) = pk;
    }
}

// ---------------- launcher ----------------
extern "C" void kernel_launch(void* const* d_in, const int* in_sizes, int n_in,
                              void* d_out, int out_size, void* d_ws, size_t ws_size,
                              hipStream_t stream) {
    const float* x    = (const float*)d_in[0];
    const float* Wq   = (const float*)d_in[1];
    const float* Wk   = (const float*)d_in[2];
    const float* Wv   = (const float*)d_in[3];
    const float* Wo   = (const float*)d_in[4];
    const float* bo   = (const float*)d_in[5];
    const float* ln1s = (const float*)d_in[6];
    const float* ln1b = (const float*)d_in[7];
    const float* ln2s = (const float*)d_in[8];
    const float* ln2b = (const float*)d_in[9];
    const float* W1   = (const float*)d_in[10];
    const float* b1   = (const float*)d_in[11];
    const float* W2   = (const float*)d_in[12];
    const float* b2   = (const float*)d_in[13];
    float* out = (float*)d_out;
    char*  wsb = (char*)d_ws;

    // workspace layout (112 MB)
    ushort_t* h_bf  = (ushort_t*)wsb;                  // 8MB  LN1 out; reused as att
    ushort_t* qb    = (ushort_t*)(wsb + (8u  << 20));  // 8MB  Q
    ushort_t* kb    = qb + 4194304;                    // 8MB  K
    ushort_t* vtb   = qb + 8388608;                    // 8MB  V^T
    float*    x1    = (float*)(wsb + (32u << 20));     // 16MB x + attn
    ushort_t* h2_bf = (ushort_t*)(wsb + (48u << 20));  // 8MB  LN2 out
    ushort_t* g_bf  = (ushort_t*)(wsb + (56u << 20));  // 32MB FFN hidden
    ushort_t* wqkv  = (ushort_t*)(wsb + (88u << 20));  // 6MB
    ushort_t* wo_b  = (ushort_t*)(wsb + (94u << 20));  // 2MB
    ushort_t* w1_b  = (ushort_t*)(wsb + (96u << 20));  // 8MB
    ushort_t* w2_b  = (ushort_t*)(wsb + (104u << 20)); // 8MB
    ushort_t* att   = h_bf;
    // split-K partial regions (4 x 8MB bf16 each):
    ushort_t* pWoB = (ushort_t*)(wsb + (56u << 20));   // g_bf region: consumed by red_ln4 BEFORE FFN-up writes g
    ushort_t* pFd  = (ushort_t*)wsb;                   // h/q/k/v region: free after Wo GEMM

    cvt_kernel<<<6144, 256, 0, stream>>>(Wq, Wk, Wv, Wo, W1, W2, wqkv, wo_b, w1_b, w2_b);
    ln_bf_kernel<<<Mrows, 256, 0, stream>>>(x, ln1s, ln1b, h_bf);
    // QKV: GN=12, GM=16 -> 192 blocks
    gemm256<0><<<192, 512, 0, stream>>>(h_bf, wqkv, nullptr, qb, Mrows, 3072, Dmod, Dmod, 12, 16);
    fattn_kernel<<<1024, 256, 0, stream>>>(qb, kb, vtb, att);
    // Wo: split-K=4 (bf16 partials), GN=4, GM=16, z=4 -> 256 blocks
    gemm256<4><<<256, 512, 0, stream>>>(att, wo_b, nullptr, pWoB, Mrows, Dmod, Dmod, Dmod / 4, 4, 16);
    red_ln4_kernel<<<Mrows, 256, 0, stream>>>(pWoB, x, bo, ln2s, ln2b, x1, h2_bf);
    // FFN up: GN=16, GM=16 -> 256 blocks
    gemm256<2><<<256, 512, 0, stream>>>(h2_bf, w1_b, b1, g_bf, Mrows, FF, Dmod, Dmod, 16, 16);
    // FFN down: split-K=4 (bf16 partials), GN=4, GM=16 -> 256 blocks
    gemm256<4><<<256, 512, 0, stream>>>(g_bf, w2_b, nullptr, pFd, Mrows, Dmod, FF, FF / 4, 4, 16);
    red_out4_kernel<<<(Mrows * Dmod / 4 + 255) / 256, 256, 0, stream>>>(pFd, x1, b2, out);
}